// Round 5
// baseline (215.521 us; speedup 1.0000x reference)
//
#include <hip/hip_runtime.h>

#define N_MOL 128
#define ATOMS 32
#define N_AT  4096
#define DIM   64
#define FEAT  187

// ---------------------------------------------------------------------------
// Kernel 1: per-molecule GNN. grid = 256 (blocks 0..127 = side D, 128..255 = A),
// block = 512 threads. Exploits block-diagonal adjacency: only the 32x32
// diagonal block of adj is ever nonzero for a molecule.
// Thread mapping for compute phases: a = tid>>4 (atom 0..31),
// d0 = (tid&15)*4 (4 consecutive dims per thread).
// ---------------------------------------------------------------------------
__global__ __launch_bounds__(512) void gnn_kernel(
    const float* __restrict__ adj_D, const float* __restrict__ adj_A,
    const int*   __restrict__ fp_D,  const int*   __restrict__ fp_A,
    const float* __restrict__ embed,
    const float* __restrict__ Wf_w,  const float* __restrict__ Wf_b,
    float* __restrict__ mol_out /* [2][N_MOL][DIM] */)
{
    __shared__ float v_s[ATOMS][DIM];     // 8 KB
    __shared__ float h_s[ATOMS][DIM];     // 8 KB
    __shared__ float adj_s[ATOMS][ATOMS]; // 4 KB
    __shared__ float w_s[DIM][DIM];       // 16 KB (one layer at a time)
    __shared__ float b_s[DIM];

    const int blk  = blockIdx.x;
    const int side = blk >> 7;   // 0 = D, 1 = A
    const int m    = blk & 127;
    const float* adj = side ? adj_A : adj_D;
    const int*   fp  = side ? fp_A  : fp_D;

    const int tid = threadIdx.x;

    // Stage 32x32 adjacency block (rows m*32..m*32+31, same cols)
    for (int i = tid; i < ATOMS * ATOMS; i += 512) {
        int r = i >> 5, c = i & 31;
        adj_s[r][c] = adj[(size_t)(m * ATOMS + r) * N_AT + (m * ATOMS + c)];
    }
    // Stage v = embed[fp]
    for (int i = tid; i < ATOMS * DIM; i += 512) {
        int a = i >> 6, d = i & 63;
        v_s[a][d] = embed[(size_t)fp[m * ATOMS + a] * DIM + d];
    }

    const int a  = tid >> 4;
    const int d0 = (tid & 15) * 4;

    for (int l = 0; l < 3; ++l) {
        // Stage this layer's weights into LDS
        for (int i = tid; i < DIM * DIM; i += 512)
            ((float*)w_s)[i] = Wf_w[l * DIM * DIM + i];
        if (tid < DIM) b_s[tid] = Wf_b[l * DIM + tid];
        __syncthreads();

        // h[a][d] = relu(b[d] + sum_k v[a][k] * W[d][k])
        float acc[4];
        #pragma unroll
        for (int j = 0; j < 4; ++j) acc[j] = b_s[d0 + j];
        for (int k = 0; k < DIM; ++k) {
            float vk = v_s[a][k];
            #pragma unroll
            for (int j = 0; j < 4; ++j) acc[j] += vk * w_s[d0 + j][k];
        }
        #pragma unroll
        for (int j = 0; j < 4; ++j) h_s[a][d0 + j] = fmaxf(acc[j], 0.0f);
        __syncthreads();

        // t = h + adj_blk @ h, then row-wise l2 normalize -> v
        float t[4];
        #pragma unroll
        for (int j = 0; j < 4; ++j) t[j] = h_s[a][d0 + j];
        for (int b = 0; b < ATOMS; ++b) {
            float ab = adj_s[a][b];
            #pragma unroll
            for (int j = 0; j < 4; ++j) t[j] += ab * h_s[b][d0 + j];
        }
        float ss = t[0]*t[0] + t[1]*t[1] + t[2]*t[2] + t[3]*t[3];
        #pragma unroll
        for (int msk = 1; msk < 16; msk <<= 1)
            ss += __shfl_xor(ss, msk);
        float scale = 1.0f / fmaxf(sqrtf(ss), 1e-12f);
        #pragma unroll
        for (int j = 0; j < 4; ++j) v_s[a][d0 + j] = t[j] * scale;
        __syncthreads();
    }

    // Sum-pool over atoms
    if (tid < DIM) {
        float s = 0.0f;
        for (int aa = 0; aa < ATOMS; ++aa) s += v_s[aa][tid];
        mol_out[(size_t)side * N_MOL * DIM + m * DIM + tid] = s;
    }
}

// ---------------------------------------------------------------------------
// Kernel 2: per-molecule head MLP. grid = 128, block = 256.
// x = [mol_D(64), homo_D, lumo_D, mol_A(64), homo_A, lumo_A, desc(55)] = 187
// Two 187->187 relu layers, then pred = x . Wp + b; writes (pred-cv)^2.
// ---------------------------------------------------------------------------
__global__ __launch_bounds__(256) void head_kernel(
    const float* __restrict__ mol,     // [2][N_MOL][DIM] in ws
    const float* __restrict__ homo_D, const float* __restrict__ lumo_D,
    const float* __restrict__ homo_A, const float* __restrict__ lumo_A,
    const float* __restrict__ desc,   const float* __restrict__ cv,
    const float* __restrict__ Wo_w,   const float* __restrict__ Wo_b,
    const float* __restrict__ Wp_w,   const float* __restrict__ Wp_b,
    float* __restrict__ sq_out /* [N_MOL] */)
{
    __shared__ float x_s[FEAT];
    __shared__ float y_s[FEAT];
    __shared__ float red_s[256];

    const int m = blockIdx.x;
    const int t = threadIdx.x;

    // Build input vector
    if (t < 64) x_s[t] = mol[m * DIM + t];
    if (t >= 64 && t < 128) x_s[66 + (t - 64)] = mol[N_MOL * DIM + m * DIM + (t - 64)];
    if (t >= 128 && t < 183) x_s[132 + (t - 128)] = desc[m * 55 + (t - 128)];
    if (t == 183) x_s[64]  = homo_D[m];
    if (t == 184) x_s[65]  = lumo_D[m];
    if (t == 185) x_s[130] = homo_A[m];
    if (t == 186) x_s[131] = lumo_A[m];
    __syncthreads();

    float* xin  = x_s;
    float* xout = y_s;
    for (int l = 0; l < 2; ++l) {
        float acc = 0.0f;
        if (t < FEAT) {
            acc = Wo_b[l * FEAT + t];
            const float* wr = Wo_w + ((size_t)l * FEAT + t) * FEAT;
            for (int k = 0; k < FEAT; ++k) acc += xin[k] * wr[k];
            acc = fmaxf(acc, 0.0f);
        }
        __syncthreads();
        if (t < FEAT) xout[t] = acc;
        __syncthreads();
        float* tmp = xin; xin = xout; xout = tmp;
    }

    // pred = xin . Wp_w + Wp_b
    red_s[t] = (t < FEAT) ? xin[t] * Wp_w[t] : 0.0f;
    __syncthreads();
    for (int s = 128; s > 0; s >>= 1) {
        if (t < s) red_s[t] += red_s[t + s];
        __syncthreads();
    }
    if (t == 0) {
        float pred = red_s[0] + Wp_b[0];
        float d = pred - cv[m];
        sq_out[m] = d * d;
    }
}

// ---------------------------------------------------------------------------
// Kernel 3: mean of 128 squared errors -> loss scalar.
// ---------------------------------------------------------------------------
__global__ __launch_bounds__(64) void loss_kernel(
    const float* __restrict__ sq, float* __restrict__ out)
{
    const int t = threadIdx.x;
    float v = sq[t] + sq[t + 64];
    #pragma unroll
    for (int msk = 32; msk >= 1; msk >>= 1)
        v += __shfl_xor(v, msk);
    if (t == 0) out[0] = v * (1.0f / 128.0f);
}

extern "C" void kernel_launch(void* const* d_in, const int* in_sizes, int n_in,
                              void* d_out, int out_size, void* d_ws, size_t ws_size,
                              hipStream_t stream) {
    const float* adj_D  = (const float*)d_in[0];
    const float* adj_A  = (const float*)d_in[1];
    const int*   fp_D   = (const int*)  d_in[2];
    const int*   fp_A   = (const int*)  d_in[3];
    // d_in[4], d_in[5]: seg_D/seg_A — structure is known (blocks of 32), unused
    const float* homo_D = (const float*)d_in[6];
    const float* lumo_D = (const float*)d_in[7];
    const float* homo_A = (const float*)d_in[8];
    const float* lumo_A = (const float*)d_in[9];
    const float* desc   = (const float*)d_in[10];
    const float* cv     = (const float*)d_in[11];
    const float* embed  = (const float*)d_in[12];
    const float* Wf_w   = (const float*)d_in[13];
    const float* Wf_b   = (const float*)d_in[14];
    const float* Wo_w   = (const float*)d_in[15];
    const float* Wo_b   = (const float*)d_in[16];
    const float* Wp_w   = (const float*)d_in[17];
    const float* Wp_b   = (const float*)d_in[18];

    float* ws  = (float*)d_ws;
    float* mol = ws;                       // 2*128*64 floats
    float* sq  = ws + 2 * N_MOL * DIM;     // 128 floats

    gnn_kernel<<<256, 512, 0, stream>>>(adj_D, adj_A, fp_D, fp_A, embed,
                                        Wf_w, Wf_b, mol);
    head_kernel<<<N_MOL, 256, 0, stream>>>(mol, homo_D, lumo_D, homo_A, lumo_A,
                                           desc, cv, Wo_w, Wo_b, Wp_w, Wp_b, sq);
    loss_kernel<<<1, 64, 0, stream>>>(sq, (float*)d_out);
}

// Round 8
// 200.223 us; speedup vs baseline: 1.0764x; 1.0764x over previous
//
#include <hip/hip_runtime.h>

#define N_MOL 128
#define ATOMS 32
#define N_AT  4096
#define DIM   64
#define FEAT  187
#define PADV  68   // v_s/h_s row stride: 68%32=4 -> conflict-free float4 rows
#define PADA  33   // adj_s row stride

// ---------------------------------------------------------------------------
// Kernel 1: per-molecule GNN. grid = 256 (blocks 0..127 side D, 128..255 side A),
// block = 512. Block-diagonal adjacency: only the 32x32 diagonal block is read.
// Bank-conflict-free LDS design (round-5 fix):
//  - W stored TRANSPOSED wT[k][d] with d-group XOR-swizzled by (k&15):
//    each thread ds_read_b128's its 4 contiguous outputs; 16 distinct addrs
//    spread over 8 bank groups (was: 16-way b32 conflict on column reads).
//  - v_s/h_s padded to 68 floats/row, adj_s to 33 -> strides not ≡0 mod 32.
//  - all 3 layers' weights staged once at prologue (LDS 70KB, 1 block/CU).
// Thread map: a = tid>>4 (atom), g = tid&15, d0 = 4g.
// ---------------------------------------------------------------------------
__global__ __launch_bounds__(512) void gnn_kernel(
    const float* __restrict__ adj_D, const float* __restrict__ adj_A,
    const int*   __restrict__ fp_D,  const int*   __restrict__ fp_A,
    const float* __restrict__ embed,
    const float* __restrict__ Wf_w,  const float* __restrict__ Wf_b,
    float* __restrict__ mol_out /* [2][N_MOL][DIM] */)
{
    __shared__ float wT_s[3][DIM][DIM];   // 48 KB, [l][k][swizzled d]
    __shared__ float b_s[3][DIM];
    __shared__ float v_s[ATOMS][PADV];    // 8.7 KB
    __shared__ float h_s[ATOMS][PADV];    // 8.7 KB
    __shared__ float adj_s[ATOMS][PADA];  // 4.2 KB

    const int blk  = blockIdx.x;
    const int side = blk >> 7;
    const int m    = blk & 127;
    const float* adj = side ? adj_A : adj_D;
    const int*   fp  = side ? fp_A  : fp_D;
    const int tid = threadIdx.x;

    // ---- Stage all weights, transposed + group-swizzled. 3*4096 floats. ----
    // Global read coalesced float4; LDS scatter writes (one-time cost).
    for (int i4 = tid; i4 < 3 * DIM * DIM / 4; i4 += 512) {
        float4 w = ((const float4*)Wf_w)[i4];
        int i  = i4 << 2;              // flat = l*4096 + d*64 + k0
        int l  = i >> 12;
        int d  = (i >> 6) & 63;
        int k0 = i & 63;               // multiple of 4, d constant across the 4
        const float* wp = (const float*)&w;
        #pragma unroll
        for (int kk = 0; kk < 4; ++kk) {
            int k  = k0 + kk;
            int dg = (d >> 2) ^ (k & 15);
            wT_s[l][k][(dg << 2) + (d & 3)] = wp[kk];
        }
    }
    if (tid < 3 * DIM) ((float*)b_s)[tid] = Wf_b[tid];

    // ---- Stage 32x32 adjacency block (float4 rows, 16B-aligned) ----
    for (int i4 = tid; i4 < ATOMS * ATOMS / 4; i4 += 512) {
        int r  = i4 >> 3;
        int c4 = (i4 & 7) << 2;
        float4 av = *(const float4*)&adj[(size_t)(m * ATOMS + r) * N_AT + m * ATOMS + c4];
        adj_s[r][c4 + 0] = av.x; adj_s[r][c4 + 1] = av.y;
        adj_s[r][c4 + 2] = av.z; adj_s[r][c4 + 3] = av.w;
    }
    // ---- Stage v = embed[fp] (512 float4 = one per thread) ----
    {
        int a  = tid >> 4;
        int d4 = (tid & 15) << 2;
        float4 ev = *(const float4*)&embed[(size_t)fp[m * ATOMS + a] * DIM + d4];
        *(float4*)&v_s[a][d4] = ev;
    }
    __syncthreads();

    const int a  = tid >> 4;
    const int g  = tid & 15;
    const int d0 = g << 2;

    for (int l = 0; l < 3; ++l) {
        // h[a][d0..d0+3] = relu(b + sum_k v[a][k] * W[d][k]), W read as wT[k][d]
        float accv[4];
        *(float4*)accv = *(const float4*)&b_s[l][d0];
        const float* vrow = v_s[a];
        #pragma unroll
        for (int k0 = 0; k0 < DIM; k0 += 4) {
            float4 vv = *(const float4*)&vrow[k0];
            const float* vp = (const float*)&vv;
            #pragma unroll
            for (int kk = 0; kk < 4; ++kk) {
                int k = k0 + kk;
                float4 ww = *(const float4*)&wT_s[l][k][(g ^ (k & 15)) << 2];
                float vs = vp[kk];
                accv[0] += vs * ww.x; accv[1] += vs * ww.y;
                accv[2] += vs * ww.z; accv[3] += vs * ww.w;
            }
        }
        float4 hst;
        hst.x = fmaxf(accv[0], 0.0f); hst.y = fmaxf(accv[1], 0.0f);
        hst.z = fmaxf(accv[2], 0.0f); hst.w = fmaxf(accv[3], 0.0f);
        *(float4*)&h_s[a][d0] = hst;
        __syncthreads();

        // t = h + adj_blk @ h ; row l2-normalize -> v
        float4 tv = *(const float4*)&h_s[a][d0];
        float t0 = tv.x, t1 = tv.y, t2 = tv.z, t3 = tv.w;
        const float* arow = adj_s[a];
        #pragma unroll 8
        for (int b = 0; b < ATOMS; ++b) {
            float ab = arow[b];
            float4 hb = *(const float4*)&h_s[b][d0];
            t0 += ab * hb.x; t1 += ab * hb.y; t2 += ab * hb.z; t3 += ab * hb.w;
        }
        float ss = t0 * t0 + t1 * t1 + t2 * t2 + t3 * t3;
        #pragma unroll
        for (int msk = 1; msk < 16; msk <<= 1)
            ss += __shfl_xor(ss, msk);
        float scale = 1.0f / fmaxf(sqrtf(ss), 1e-12f);
        float4 sv; sv.x = t0 * scale; sv.y = t1 * scale; sv.z = t2 * scale; sv.w = t3 * scale;
        *(float4*)&v_s[a][d0] = sv;
        __syncthreads();
    }

    // Sum-pool over atoms (lanes read column tid: stride 68 -> conflict-free)
    if (tid < DIM) {
        float s = 0.0f;
        #pragma unroll 8
        for (int aa = 0; aa < ATOMS; ++aa) s += v_s[aa][tid];
        mol_out[(size_t)side * N_MOL * DIM + m * DIM + tid] = s;
    }
}

// ---------------------------------------------------------------------------
// Kernel 2: per-molecule head MLP. grid = 128, block = 256.
// ---------------------------------------------------------------------------
__global__ __launch_bounds__(256) void head_kernel(
    const float* __restrict__ mol,
    const float* __restrict__ homo_D, const float* __restrict__ lumo_D,
    const float* __restrict__ homo_A, const float* __restrict__ lumo_A,
    const float* __restrict__ desc,   const float* __restrict__ cv,
    const float* __restrict__ Wo_w,   const float* __restrict__ Wo_b,
    const float* __restrict__ Wp_w,   const float* __restrict__ Wp_b,
    float* __restrict__ sq_out /* [N_MOL] */)
{
    __shared__ float x_s[FEAT + 1];
    __shared__ float y_s[FEAT + 1];
    __shared__ float red_s[256];

    const int m = blockIdx.x;
    const int t = threadIdx.x;

    if (t < 64) x_s[t] = mol[m * DIM + t];
    if (t >= 64 && t < 128) x_s[66 + (t - 64)] = mol[N_MOL * DIM + m * DIM + (t - 64)];
    if (t >= 128 && t < 183) x_s[132 + (t - 128)] = desc[m * 55 + (t - 128)];
    if (t == 183) x_s[64]  = homo_D[m];
    if (t == 184) x_s[65]  = lumo_D[m];
    if (t == 185) x_s[130] = homo_A[m];
    if (t == 186) x_s[131] = lumo_A[m];
    __syncthreads();

    float* xin  = x_s;
    float* xout = y_s;
    for (int l = 0; l < 2; ++l) {
        float acc = 0.0f;
        if (t < FEAT) {
            acc = Wo_b[l * FEAT + t];
            const float* wr = Wo_w + ((size_t)l * FEAT + t) * FEAT;
            int k = 0;
            #pragma unroll 1
            for (; k < 184; k += 4) {
                acc += xin[k] * wr[k] + xin[k+1] * wr[k+1]
                     + xin[k+2] * wr[k+2] + xin[k+3] * wr[k+3];
            }
            acc += xin[184] * wr[184] + xin[185] * wr[185] + xin[186] * wr[186];
            acc = fmaxf(acc, 0.0f);
        }
        __syncthreads();
        if (t < FEAT) xout[t] = acc;
        __syncthreads();
        float* tmp = xin; xin = xout; xout = tmp;
    }

    red_s[t] = (t < FEAT) ? xin[t] * Wp_w[t] : 0.0f;
    __syncthreads();
    for (int s = 128; s > 0; s >>= 1) {
        if (t < s) red_s[t] += red_s[t + s];
        __syncthreads();
    }
    if (t == 0) {
        float pred = red_s[0] + Wp_b[0];
        float d = pred - cv[m];
        sq_out[m] = d * d;
    }
}

// ---------------------------------------------------------------------------
// Kernel 3: mean of 128 squared errors -> loss scalar.
// ---------------------------------------------------------------------------
__global__ __launch_bounds__(64) void loss_kernel(
    const float* __restrict__ sq, float* __restrict__ out)
{
    const int t = threadIdx.x;
    float v = sq[t] + sq[t + 64];
    #pragma unroll
    for (int msk = 32; msk >= 1; msk >>= 1)
        v += __shfl_xor(v, msk);
    if (t == 0) out[0] = v * (1.0f / 128.0f);
}

extern "C" void kernel_launch(void* const* d_in, const int* in_sizes, int n_in,
                              void* d_out, int out_size, void* d_ws, size_t ws_size,
                              hipStream_t stream) {
    const float* adj_D  = (const float*)d_in[0];
    const float* adj_A  = (const float*)d_in[1];
    const int*   fp_D   = (const int*)  d_in[2];
    const int*   fp_A   = (const int*)  d_in[3];
    const float* homo_D = (const float*)d_in[6];
    const float* lumo_D = (const float*)d_in[7];
    const float* homo_A = (const float*)d_in[8];
    const float* lumo_A = (const float*)d_in[9];
    const float* desc   = (const float*)d_in[10];
    const float* cv     = (const float*)d_in[11];
    const float* embed  = (const float*)d_in[12];
    const float* Wf_w   = (const float*)d_in[13];
    const float* Wf_b   = (const float*)d_in[14];
    const float* Wo_w   = (const float*)d_in[15];
    const float* Wo_b   = (const float*)d_in[16];
    const float* Wp_w   = (const float*)d_in[17];
    const float* Wp_b   = (const float*)d_in[18];

    float* ws  = (float*)d_ws;
    float* mol = ws;                       // 2*128*64 floats
    float* sq  = ws + 2 * N_MOL * DIM;     // 128 floats

    gnn_kernel<<<256, 512, 0, stream>>>(adj_D, adj_A, fp_D, fp_A, embed,
                                        Wf_w, Wf_b, mol);
    head_kernel<<<N_MOL, 256, 0, stream>>>(mol, homo_D, lumo_D, homo_A, lumo_A,
                                           desc, cv, Wo_w, Wo_b, Wp_w, Wp_b, sq);
    loss_kernel<<<1, 64, 0, stream>>>(sq, (float*)d_out);
}

// Round 10
// 195.226 us; speedup vs baseline: 1.1040x; 1.0256x over previous
//
#include <hip/hip_runtime.h>

#define N_MOL 128
#define ATOMS 32
#define N_AT  4096
#define DIM   64
#define FEAT  187
#define PADV  68   // v_s/h_s row stride: 68%32=4 -> conflict-free float4 rows
#define PADA  33   // adj_s row stride

// ---------------------------------------------------------------------------
// Kernel 1: per-molecule GNN. grid = 256 (blocks 0..127 side D, 128..255 side A),
// block = 512. Block-diagonal adjacency: only the 32x32 diagonal block is read.
// Bank-conflict-free LDS (round-5 fix, verified: SQ_LDS_BANK_CONFLICT -> 0).
// Round-8 change: epilogue writes pooled features DIRECTLY into the
// feature-major head activation buffer xT[feat][mol] (rows side*66+d), and
// side-0 blocks also fill homo/lumo/desc rows -> concat costs no launch.
// ---------------------------------------------------------------------------
__global__ __launch_bounds__(512) void gnn_kernel(
    const float* __restrict__ adj_D, const float* __restrict__ adj_A,
    const int*   __restrict__ fp_D,  const int*   __restrict__ fp_A,
    const float* __restrict__ embed,
    const float* __restrict__ Wf_w,  const float* __restrict__ Wf_b,
    const float* __restrict__ homo_D, const float* __restrict__ lumo_D,
    const float* __restrict__ homo_A, const float* __restrict__ lumo_A,
    const float* __restrict__ desc,
    float* __restrict__ xT /* [FEAT][N_MOL] feature-major */)
{
    __shared__ float wT_s[3][DIM][DIM];   // 48 KB, [l][k][swizzled d]
    __shared__ float b_s[3][DIM];
    __shared__ float v_s[ATOMS][PADV];
    __shared__ float h_s[ATOMS][PADV];
    __shared__ float adj_s[ATOMS][PADA];

    const int blk  = blockIdx.x;
    const int side = blk >> 7;
    const int m    = blk & 127;
    const float* adj = side ? adj_A : adj_D;
    const int*   fp  = side ? fp_A  : fp_D;
    const int tid = threadIdx.x;

    // ---- Stage all weights, transposed + group-swizzled ----
    for (int i4 = tid; i4 < 3 * DIM * DIM / 4; i4 += 512) {
        float4 w = ((const float4*)Wf_w)[i4];
        int i  = i4 << 2;              // flat = l*4096 + d*64 + k0
        int l  = i >> 12;
        int d  = (i >> 6) & 63;
        int k0 = i & 63;
        const float* wp = (const float*)&w;
        #pragma unroll
        for (int kk = 0; kk < 4; ++kk) {
            int k  = k0 + kk;
            int dg = (d >> 2) ^ (k & 15);
            wT_s[l][k][(dg << 2) + (d & 3)] = wp[kk];
        }
    }
    if (tid < 3 * DIM) ((float*)b_s)[tid] = Wf_b[tid];

    // ---- Stage 32x32 adjacency block ----
    for (int i4 = tid; i4 < ATOMS * ATOMS / 4; i4 += 512) {
        int r  = i4 >> 3;
        int c4 = (i4 & 7) << 2;
        float4 av = *(const float4*)&adj[(size_t)(m * ATOMS + r) * N_AT + m * ATOMS + c4];
        adj_s[r][c4 + 0] = av.x; adj_s[r][c4 + 1] = av.y;
        adj_s[r][c4 + 2] = av.z; adj_s[r][c4 + 3] = av.w;
    }
    // ---- Stage v = embed[fp] ----
    {
        int a  = tid >> 4;
        int d4 = (tid & 15) << 2;
        float4 ev = *(const float4*)&embed[(size_t)fp[m * ATOMS + a] * DIM + d4];
        *(float4*)&v_s[a][d4] = ev;
    }
    __syncthreads();

    const int a  = tid >> 4;
    const int g  = tid & 15;
    const int d0 = g << 2;

    for (int l = 0; l < 3; ++l) {
        float accv[4];
        *(float4*)accv = *(const float4*)&b_s[l][d0];
        const float* vrow = v_s[a];
        #pragma unroll
        for (int k0 = 0; k0 < DIM; k0 += 4) {
            float4 vv = *(const float4*)&vrow[k0];
            const float* vp = (const float*)&vv;
            #pragma unroll
            for (int kk = 0; kk < 4; ++kk) {
                int k = k0 + kk;
                float4 ww = *(const float4*)&wT_s[l][k][(g ^ (k & 15)) << 2];
                float vs = vp[kk];
                accv[0] += vs * ww.x; accv[1] += vs * ww.y;
                accv[2] += vs * ww.z; accv[3] += vs * ww.w;
            }
        }
        float4 hst;
        hst.x = fmaxf(accv[0], 0.0f); hst.y = fmaxf(accv[1], 0.0f);
        hst.z = fmaxf(accv[2], 0.0f); hst.w = fmaxf(accv[3], 0.0f);
        *(float4*)&h_s[a][d0] = hst;
        __syncthreads();

        float4 tv = *(const float4*)&h_s[a][d0];
        float t0 = tv.x, t1 = tv.y, t2 = tv.z, t3 = tv.w;
        const float* arow = adj_s[a];
        #pragma unroll 8
        for (int b = 0; b < ATOMS; ++b) {
            float ab = arow[b];
            float4 hb = *(const float4*)&h_s[b][d0];
            t0 += ab * hb.x; t1 += ab * hb.y; t2 += ab * hb.z; t3 += ab * hb.w;
        }
        float ss = t0 * t0 + t1 * t1 + t2 * t2 + t3 * t3;
        #pragma unroll
        for (int msk = 1; msk < 16; msk <<= 1)
            ss += __shfl_xor(ss, msk);
        float scale = 1.0f / fmaxf(sqrtf(ss), 1e-12f);
        float4 sv; sv.x = t0 * scale; sv.y = t1 * scale; sv.z = t2 * scale; sv.w = t3 * scale;
        *(float4*)&v_s[a][d0] = sv;
        __syncthreads();
    }

    // ---- Epilogue: sum-pool -> xT rows (feature-major) + concat fills ----
    if (tid < DIM) {
        float s = 0.0f;
        #pragma unroll 8
        for (int aa = 0; aa < ATOMS; ++aa) s += v_s[aa][tid];
        xT[(side * 66 + tid) * N_MOL + m] = s;   // rows 0..63 / 66..129
    }
    if (side == 0) {
        if (tid == 64) xT[64 * N_MOL + m]  = homo_D[m];
        if (tid == 65) xT[65 * N_MOL + m]  = lumo_D[m];
        if (tid == 66) xT[130 * N_MOL + m] = homo_A[m];
        if (tid == 67) xT[131 * N_MOL + m] = lumo_A[m];
        if (tid >= 68 && tid < 68 + 55)
            xT[(132 + tid - 68) * N_MOL + m] = desc[m * 55 + (tid - 68)];
    }
}

// ---------------------------------------------------------------------------
// Kernel 2: one head layer in feature-major layout.
// grid = 187 (one block per output feature f), block = 128 (one thread per mol).
// wr[k] is block-uniform (scalar load); xT_in[k*128+m] is fully coalesced.
// ---------------------------------------------------------------------------
__global__ __launch_bounds__(128) void head_layer_kernel(
    const float* __restrict__ xT_in,  // [FEAT][N_MOL]
    float* __restrict__ xT_out,       // [FEAT][N_MOL]
    const float* __restrict__ W,      // [FEAT][FEAT] (pre-offset for layer)
    const float* __restrict__ b)      // [FEAT]       (pre-offset)
{
    const int f = blockIdx.x;
    const int m = threadIdx.x;
    const float* wr = W + (size_t)f * FEAT;

    float acc = b[f];
    int k = 0;
    #pragma unroll 2
    for (; k + 8 <= FEAT; k += 8) {
        float acc0 = wr[k+0] * xT_in[(k+0) * N_MOL + m]
                   + wr[k+1] * xT_in[(k+1) * N_MOL + m]
                   + wr[k+2] * xT_in[(k+2) * N_MOL + m]
                   + wr[k+3] * xT_in[(k+3) * N_MOL + m];
        float acc1 = wr[k+4] * xT_in[(k+4) * N_MOL + m]
                   + wr[k+5] * xT_in[(k+5) * N_MOL + m]
                   + wr[k+6] * xT_in[(k+6) * N_MOL + m]
                   + wr[k+7] * xT_in[(k+7) * N_MOL + m];
        acc += acc0 + acc1;
    }
    for (; k < FEAT; ++k) acc += wr[k] * xT_in[k * N_MOL + m];

    xT_out[(size_t)f * N_MOL + m] = fmaxf(acc, 0.0f);
}

// ---------------------------------------------------------------------------
// Kernel 3: prediction + MSE loss. 1 block, 128 threads (one per molecule).
// pred[m] = sum_f Wp_w[f] * xT[f][m] + Wp_b; out = mean((pred-cv)^2).
// ---------------------------------------------------------------------------
__global__ __launch_bounds__(128) void predloss_kernel(
    const float* __restrict__ xT,   // [FEAT][N_MOL] (final activations)
    const float* __restrict__ Wp_w, const float* __restrict__ Wp_b,
    const float* __restrict__ cv,
    float* __restrict__ out)
{
    __shared__ float p_s[2];
    const int m = threadIdx.x;

    float acc = Wp_b[0];
    int f = 0;
    #pragma unroll 2
    for (; f + 8 <= FEAT; f += 8) {
        float a0 = Wp_w[f+0] * xT[(f+0) * N_MOL + m]
                 + Wp_w[f+1] * xT[(f+1) * N_MOL + m]
                 + Wp_w[f+2] * xT[(f+2) * N_MOL + m]
                 + Wp_w[f+3] * xT[(f+3) * N_MOL + m];
        float a1 = Wp_w[f+4] * xT[(f+4) * N_MOL + m]
                 + Wp_w[f+5] * xT[(f+5) * N_MOL + m]
                 + Wp_w[f+6] * xT[(f+6) * N_MOL + m]
                 + Wp_w[f+7] * xT[(f+7) * N_MOL + m];
        acc += a0 + a1;
    }
    for (; f < FEAT; ++f) acc += Wp_w[f] * xT[f * N_MOL + m];

    float d = acc - cv[m];
    float v = d * d;
    #pragma unroll
    for (int msk = 32; msk >= 1; msk >>= 1)
        v += __shfl_xor(v, msk);
    if ((m & 63) == 0) p_s[m >> 6] = v;
    __syncthreads();
    if (m == 0) out[0] = (p_s[0] + p_s[1]) * (1.0f / 128.0f);
}

extern "C" void kernel_launch(void* const* d_in, const int* in_sizes, int n_in,
                              void* d_out, int out_size, void* d_ws, size_t ws_size,
                              hipStream_t stream) {
    const float* adj_D  = (const float*)d_in[0];
    const float* adj_A  = (const float*)d_in[1];
    const int*   fp_D   = (const int*)  d_in[2];
    const int*   fp_A   = (const int*)  d_in[3];
    const float* homo_D = (const float*)d_in[6];
    const float* lumo_D = (const float*)d_in[7];
    const float* homo_A = (const float*)d_in[8];
    const float* lumo_A = (const float*)d_in[9];
    const float* desc   = (const float*)d_in[10];
    const float* cv     = (const float*)d_in[11];
    const float* embed  = (const float*)d_in[12];
    const float* Wf_w   = (const float*)d_in[13];
    const float* Wf_b   = (const float*)d_in[14];
    const float* Wo_w   = (const float*)d_in[15];
    const float* Wo_b   = (const float*)d_in[16];
    const float* Wp_w   = (const float*)d_in[17];
    const float* Wp_b   = (const float*)d_in[18];

    float* ws  = (float*)d_ws;
    float* xT0 = ws;                        // [187][128]
    float* xT1 = ws + FEAT * N_MOL;         // [187][128]

    gnn_kernel<<<256, 512, 0, stream>>>(adj_D, adj_A, fp_D, fp_A, embed,
                                        Wf_w, Wf_b,
                                        homo_D, lumo_D, homo_A, lumo_A, desc,
                                        xT0);
    head_layer_kernel<<<FEAT, 128, 0, stream>>>(xT0, xT1, Wo_w, Wo_b);
    head_layer_kernel<<<FEAT, 128, 0, stream>>>(xT1, xT0,
                                                Wo_w + (size_t)FEAT * FEAT,
                                                Wo_b + FEAT);
    predloss_kernel<<<1, 128, 0, stream>>>(xT0, Wp_w, Wp_b, cv, (float*)d_out);
}

// Round 13
// 194.407 us; speedup vs baseline: 1.1086x; 1.0042x over previous
//
#include <hip/hip_runtime.h>

#define N_MOL 128
#define ATOMS 32
#define N_AT  4096
#define DIM   64
#define FEAT  187
#define PADV  68   // v_s/h_s row stride: 68%32=4 -> conflict-free float4 rows
#define PADA  33   // adj_s row stride

// ---------------------------------------------------------------------------
// Kernel 0: bake transposed+swizzled GNN weight image into ws (once/launch).
// img[l][k][((d>>2)^(k&15))<<2 | (d&3)] = Wf_w[l][d][k]. 12288 floats.
// Coalesced float4 reads, scattered global writes (trivial size).
// ---------------------------------------------------------------------------
__global__ __launch_bounds__(512) void prep_kernel(
    const float* __restrict__ Wf_w, float* __restrict__ img)
{
    int i4 = blockIdx.x * 512 + threadIdx.x;   // grid 6 x 512 = 3072 float4
    if (i4 >= 3 * DIM * DIM / 4) return;
    float4 w = ((const float4*)Wf_w)[i4];
    int i  = i4 << 2;              // flat = l*4096 + d*64 + k0
    int l  = i >> 12;
    int d  = (i >> 6) & 63;
    int k0 = i & 63;
    const float* wp = (const float*)&w;
    #pragma unroll
    for (int kk = 0; kk < 4; ++kk) {
        int k  = k0 + kk;
        int dg = (d >> 2) ^ (k & 15);
        img[l * DIM * DIM + k * DIM + (dg << 2) + (d & 3)] = wp[kk];
    }
}

// ---------------------------------------------------------------------------
// Kernel 1: per-molecule GNN. grid = 256 (0..127 side D, 128..255 side A),
// block = 512. Block-diagonal adjacency: only the 32x32 diagonal block read.
// Round-10 change: weight staging is now a LINEAR float4 copy of the
// pre-swizzled image (was: 8-way bank-conflicted scatter writes/block).
// Read-side layout identical to round-8 (verified exact, absmax 0.0).
// ---------------------------------------------------------------------------
__global__ __launch_bounds__(512) void gnn_kernel(
    const float* __restrict__ adj_D, const float* __restrict__ adj_A,
    const int*   __restrict__ fp_D,  const int*   __restrict__ fp_A,
    const float* __restrict__ embed,
    const float* __restrict__ wimg,  const float* __restrict__ Wf_b,
    const float* __restrict__ homo_D, const float* __restrict__ lumo_D,
    const float* __restrict__ homo_A, const float* __restrict__ lumo_A,
    const float* __restrict__ desc,
    float* __restrict__ xT /* [FEAT][N_MOL] feature-major */)
{
    __shared__ float wT_s[3][DIM][DIM];   // 48 KB, [l][k][swizzled d]
    __shared__ float b_s[3][DIM];
    __shared__ float v_s[ATOMS][PADV];
    __shared__ float h_s[ATOMS][PADV];
    __shared__ float adj_s[ATOMS][PADA];

    const int blk  = blockIdx.x;
    const int side = blk >> 7;
    const int m    = blk & 127;
    const float* adj = side ? adj_A : adj_D;
    const int*   fp  = side ? fp_A  : fp_D;
    const int tid = threadIdx.x;

    // ---- Stage weights: linear float4 copy, conflict-free both sides ----
    {
        float4* dst = (float4*)wT_s;
        const float4* src = (const float4*)wimg;
        #pragma unroll
        for (int it = 0; it < 6; ++it)
            dst[tid + it * 512] = src[tid + it * 512];
    }
    if (tid < 3 * DIM) ((float*)b_s)[tid] = Wf_b[tid];

    // ---- Stage 32x32 adjacency block ----
    for (int i4 = tid; i4 < ATOMS * ATOMS / 4; i4 += 512) {
        int r  = i4 >> 3;
        int c4 = (i4 & 7) << 2;
        float4 av = *(const float4*)&adj[(size_t)(m * ATOMS + r) * N_AT + m * ATOMS + c4];
        adj_s[r][c4 + 0] = av.x; adj_s[r][c4 + 1] = av.y;
        adj_s[r][c4 + 2] = av.z; adj_s[r][c4 + 3] = av.w;
    }
    // ---- Stage v = embed[fp] ----
    {
        int a  = tid >> 4;
        int d4 = (tid & 15) << 2;
        float4 ev = *(const float4*)&embed[(size_t)fp[m * ATOMS + a] * DIM + d4];
        *(float4*)&v_s[a][d4] = ev;
    }
    __syncthreads();

    const int a  = tid >> 4;
    const int g  = tid & 15;
    const int d0 = g << 2;

    for (int l = 0; l < 3; ++l) {
        float accv[4];
        *(float4*)accv = *(const float4*)&b_s[l][d0];
        const float* vrow = v_s[a];
        #pragma unroll
        for (int k0 = 0; k0 < DIM; k0 += 4) {
            float4 vv = *(const float4*)&vrow[k0];
            const float* vp = (const float*)&vv;
            #pragma unroll
            for (int kk = 0; kk < 4; ++kk) {
                int k = k0 + kk;
                float4 ww = *(const float4*)&wT_s[l][k][(g ^ (k & 15)) << 2];
                float vs = vp[kk];
                accv[0] += vs * ww.x; accv[1] += vs * ww.y;
                accv[2] += vs * ww.z; accv[3] += vs * ww.w;
            }
        }
        float4 hst;
        hst.x = fmaxf(accv[0], 0.0f); hst.y = fmaxf(accv[1], 0.0f);
        hst.z = fmaxf(accv[2], 0.0f); hst.w = fmaxf(accv[3], 0.0f);
        *(float4*)&h_s[a][d0] = hst;
        __syncthreads();

        float4 tv = *(const float4*)&h_s[a][d0];
        float t0 = tv.x, t1 = tv.y, t2 = tv.z, t3 = tv.w;
        const float* arow = adj_s[a];
        #pragma unroll 8
        for (int b = 0; b < ATOMS; ++b) {
            float ab = arow[b];
            float4 hb = *(const float4*)&h_s[b][d0];
            t0 += ab * hb.x; t1 += ab * hb.y; t2 += ab * hb.z; t3 += ab * hb.w;
        }
        float ss = t0 * t0 + t1 * t1 + t2 * t2 + t3 * t3;
        #pragma unroll
        for (int msk = 1; msk < 16; msk <<= 1)
            ss += __shfl_xor(ss, msk);
        float scale = 1.0f / fmaxf(sqrtf(ss), 1e-12f);
        float4 sv; sv.x = t0 * scale; sv.y = t1 * scale; sv.z = t2 * scale; sv.w = t3 * scale;
        *(float4*)&v_s[a][d0] = sv;
        __syncthreads();
    }

    // ---- Epilogue: sum-pool -> xT rows (feature-major) + concat fills ----
    if (tid < DIM) {
        float s = 0.0f;
        #pragma unroll 8
        for (int aa = 0; aa < ATOMS; ++aa) s += v_s[aa][tid];
        xT[(side * 66 + tid) * N_MOL + m] = s;   // rows 0..63 / 66..129
    }
    if (side == 0) {
        if (tid == 64) xT[64 * N_MOL + m]  = homo_D[m];
        if (tid == 65) xT[65 * N_MOL + m]  = lumo_D[m];
        if (tid == 66) xT[130 * N_MOL + m] = homo_A[m];
        if (tid == 67) xT[131 * N_MOL + m] = lumo_A[m];
        if (tid >= 68 && tid < 68 + 55)
            xT[(132 + tid - 68) * N_MOL + m] = desc[m * 55 + (tid - 68)];
    }
}

// ---------------------------------------------------------------------------
// Kernel 2: one head layer in feature-major layout.
// grid = 187 (block per output feature), block = 128 (thread per molecule).
// wr[k] block-uniform (scalar loads); xT_in[k*128+m] fully coalesced.
// ---------------------------------------------------------------------------
__global__ __launch_bounds__(128) void head_layer_kernel(
    const float* __restrict__ xT_in,  // [FEAT][N_MOL]
    float* __restrict__ xT_out,       // [FEAT][N_MOL]
    const float* __restrict__ W,      // [FEAT][FEAT] (pre-offset for layer)
    const float* __restrict__ b)      // [FEAT]       (pre-offset)
{
    const int f = blockIdx.x;
    const int m = threadIdx.x;
    const float* wr = W + (size_t)f * FEAT;

    float acc = b[f];
    int k = 0;
    #pragma unroll 2
    for (; k + 8 <= FEAT; k += 8) {
        float acc0 = wr[k+0] * xT_in[(k+0) * N_MOL + m]
                   + wr[k+1] * xT_in[(k+1) * N_MOL + m]
                   + wr[k+2] * xT_in[(k+2) * N_MOL + m]
                   + wr[k+3] * xT_in[(k+3) * N_MOL + m];
        float acc1 = wr[k+4] * xT_in[(k+4) * N_MOL + m]
                   + wr[k+5] * xT_in[(k+5) * N_MOL + m]
                   + wr[k+6] * xT_in[(k+6) * N_MOL + m]
                   + wr[k+7] * xT_in[(k+7) * N_MOL + m];
        acc += acc0 + acc1;
    }
    for (; k < FEAT; ++k) acc += wr[k] * xT_in[k * N_MOL + m];

    xT_out[(size_t)f * N_MOL + m] = fmaxf(acc, 0.0f);
}

// ---------------------------------------------------------------------------
// Kernel 3: prediction + MSE loss. 1 block, 128 threads (one per molecule).
// ---------------------------------------------------------------------------
__global__ __launch_bounds__(128) void predloss_kernel(
    const float* __restrict__ xT,   // [FEAT][N_MOL] (final activations)
    const float* __restrict__ Wp_w, const float* __restrict__ Wp_b,
    const float* __restrict__ cv,
    float* __restrict__ out)
{
    __shared__ float p_s[2];
    const int m = threadIdx.x;

    float acc = Wp_b[0];
    int f = 0;
    #pragma unroll 2
    for (; f + 8 <= FEAT; f += 8) {
        float a0 = Wp_w[f+0] * xT[(f+0) * N_MOL + m]
                 + Wp_w[f+1] * xT[(f+1) * N_MOL + m]
                 + Wp_w[f+2] * xT[(f+2) * N_MOL + m]
                 + Wp_w[f+3] * xT[(f+3) * N_MOL + m];
        float a1 = Wp_w[f+4] * xT[(f+4) * N_MOL + m]
                 + Wp_w[f+5] * xT[(f+5) * N_MOL + m]
                 + Wp_w[f+6] * xT[(f+6) * N_MOL + m]
                 + Wp_w[f+7] * xT[(f+7) * N_MOL + m];
        acc += a0 + a1;
    }
    for (; f < FEAT; ++f) acc += Wp_w[f] * xT[f * N_MOL + m];

    float d = acc - cv[m];
    float v = d * d;
    #pragma unroll
    for (int msk = 32; msk >= 1; msk >>= 1)
        v += __shfl_xor(v, msk);
    if ((m & 63) == 0) p_s[m >> 6] = v;
    __syncthreads();
    if (m == 0) out[0] = (p_s[0] + p_s[1]) * (1.0f / 128.0f);
}

extern "C" void kernel_launch(void* const* d_in, const int* in_sizes, int n_in,
                              void* d_out, int out_size, void* d_ws, size_t ws_size,
                              hipStream_t stream) {
    const float* adj_D  = (const float*)d_in[0];
    const float* adj_A  = (const float*)d_in[1];
    const int*   fp_D   = (const int*)  d_in[2];
    const int*   fp_A   = (const int*)  d_in[3];
    const float* homo_D = (const float*)d_in[6];
    const float* lumo_D = (const float*)d_in[7];
    const float* homo_A = (const float*)d_in[8];
    const float* lumo_A = (const float*)d_in[9];
    const float* desc   = (const float*)d_in[10];
    const float* cv     = (const float*)d_in[11];
    const float* embed  = (const float*)d_in[12];
    const float* Wf_w   = (const float*)d_in[13];
    const float* Wf_b   = (const float*)d_in[14];
    const float* Wo_w   = (const float*)d_in[15];
    const float* Wo_b   = (const float*)d_in[16];
    const float* Wp_w   = (const float*)d_in[17];
    const float* Wp_b   = (const float*)d_in[18];

    float* ws   = (float*)d_ws;
    float* xT0  = ws;                         // [187][128]
    float* xT1  = ws + FEAT * N_MOL;          // [187][128]
    float* wimg = ws + 2 * FEAT * N_MOL;      // [3][64][64] swizzled W image

    prep_kernel<<<6, 512, 0, stream>>>(Wf_w, wimg);
    gnn_kernel<<<256, 512, 0, stream>>>(adj_D, adj_A, fp_D, fp_A, embed,
                                        wimg, Wf_b,
                                        homo_D, lumo_D, homo_A, lumo_A, desc,
                                        xT0);
    head_layer_kernel<<<FEAT, 128, 0, stream>>>(xT0, xT1, Wo_w, Wo_b);
    head_layer_kernel<<<FEAT, 128, 0, stream>>>(xT1, xT0,
                                                Wo_w + (size_t)FEAT * FEAT,
                                                Wo_b + FEAT);
    predloss_kernel<<<1, 128, 0, stream>>>(xT0, Wp_w, Wp_b, cv, (float*)d_out);
}